// Round 9
// baseline (169.387 us; speedup 1.0000x reference)
//
#include <hip/hip_runtime.h>
#include <math.h>

constexpr int BATCH = 8;
constexpr int SEQ   = 1024;
constexpr int DM    = 256;
constexpr int DF    = 2048;
constexpr int NH    = 8;
constexpr int HDIM  = 32;
constexpr int ROWS  = BATCH * SEQ;    // 8192
constexpr float NEGV = -9e15f;
constexpr float EPSV = 1e-5f;
constexpr float QSCALE = 0.2550351822f;   // 1/sqrt(32) * log2(e)
constexpr float LOG2E  = 1.44269504f;

typedef __attribute__((ext_vector_type(8))) short short8;
typedef __attribute__((ext_vector_type(4))) float f32x4;

static __device__ __forceinline__ ushort f2bf(float f) {
    unsigned x = __float_as_uint(f);
    unsigned r = (x + 0x7fffu + ((x >> 16) & 1u)) >> 16;   // RNE
    return (ushort)r;
}
static __device__ __forceinline__ unsigned cvt_pk_bf16(float lo, float hi) {
    unsigned r;
    asm volatile("v_cvt_pk_bf16_f32 %0, %1, %2" : "=v"(r) : "v"(lo), "v"(hi));
    return r;
}
// async global -> LDS, 16B per lane; LDS dest = wave-uniform base + lane*16
static __device__ __forceinline__ void gl16(const ushort* g, ushort* l) {
    __builtin_amdgcn_global_load_lds(
        (const __attribute__((address_space(1))) void*)g,
        (__attribute__((address_space(3))) void*)l, 16, 0, 0);
}

// ---------------- fused fp32 -> bf16 cast of 5 regions ----------------
struct CastArgs {
    const float* in[5];
    ushort* out[5];
    int n4[5];
};
__global__ __launch_bounds__(256) void castall_k(CastArgs a)
{
    int idx = blockIdx.x * 256 + threadIdx.x;
    #pragma unroll
    for (int r = 0; r < 5; r++) {
        if (idx < a.n4[r]) {
            float4 v = *(const float4*)&a.in[r][(size_t)idx * 4];
            ushort4 o; o.x = f2bf(v.x); o.y = f2bf(v.y); o.z = f2bf(v.z); o.w = f2bf(v.w);
            *(ushort4*)&a.out[r][(size_t)idx * 4] = o;
            return;
        }
        idx -= a.n4[r];
    }
}

// ---------------- transpose-cast: Out[c][r] = bf16(In[r][c]) ----------------
__global__ __launch_bounds__(256) void tcast_k(const float* __restrict__ In,
                                               ushort* __restrict__ Out,
                                               int R, int C)
{
    __shared__ float Ts[32][33];
    const int r0 = blockIdx.y * 32, c0 = blockIdx.x * 32;
    const int t = threadIdx.x;
    const int lr = t >> 3, lc4 = (t & 7) * 4;
    float4 v = *(const float4*)&In[(size_t)(r0 + lr) * C + c0 + lc4];
    Ts[lr][lc4] = v.x; Ts[lr][lc4 + 1] = v.y; Ts[lr][lc4 + 2] = v.z; Ts[lr][lc4 + 3] = v.w;
    __syncthreads();
    const int oc = t >> 3, or4 = (t & 7) * 4;
    ushort4 o;
    o.x = f2bf(Ts[or4 + 0][oc]); o.y = f2bf(Ts[or4 + 1][oc]);
    o.z = f2bf(Ts[or4 + 2][oc]); o.w = f2bf(Ts[or4 + 3][oc]);
    *(ushort4*)&Out[(size_t)(c0 + oc) * R + r0 + or4] = o;
}

// ---------------- w1 = W_gat @ a1, w2 = W_gat @ a2 ----------------
__global__ __launch_bounds__(256) void w12_k(const float* __restrict__ W_gat,
                                             const float* __restrict__ a_gat,
                                             float* __restrict__ w1,
                                             float* __restrict__ w2)
{
    const int t = threadIdx.x;
    const int k = blockIdx.x * 4 + (t >> 6);
    const int l = t & 63;
    float4 wv = *(const float4*)&W_gat[(size_t)k * DM + 4 * l];
    float4 a1 = *(const float4*)&a_gat[4 * l];
    float4 a2 = *(const float4*)&a_gat[DM + 4 * l];
    float s1 = wv.x*a1.x + wv.y*a1.y + wv.z*a1.z + wv.w*a1.w;
    float s2 = wv.x*a2.x + wv.y*a2.y + wv.z*a2.z + wv.w*a2.w;
    #pragma unroll
    for (int off = 32; off; off >>= 1) {
        s1 += __shfl_xor(s1, off, 64);
        s2 += __shfl_xor(s2, off, 64);
    }
    if (l == 0) { w1[k] = s1; w2[k] = s2; }
}

// ---------------- f1 = log2e*(src@w1), f2 = log2e*(src@w2) ----------------
__global__ __launch_bounds__(256) void f12_k(const float* __restrict__ src,
                                             const float* __restrict__ w1,
                                             const float* __restrict__ w2,
                                             float* __restrict__ f1,
                                             float* __restrict__ f2)
{
    const int t = threadIdx.x;
    const size_t row = (size_t)blockIdx.x * 4 + (t >> 6);
    const int l = t & 63;
    float s1 = 0.f, s2 = 0.f;
    #pragma unroll
    for (int i = 0; i < 4; i++) {
        float v = src[row * DM + l + 64*i];
        s1 = fmaf(v, w1[l + 64*i], s1);
        s2 = fmaf(v, w2[l + 64*i], s2);
    }
    #pragma unroll
    for (int off = 32; off; off >>= 1) {
        s1 += __shfl_xor(s1, off, 64);
        s2 += __shfl_xor(s2, off, 64);
    }
    if (l == 0) { f1[row] = s1 * LOG2E; f2[row] = s2 * LOG2E; }
}

// ---------------- bf16 MFMA GEMM v3: global_load_lds staging, dbuf, linear LDS ----------------
// C = act(A @ B^T + bias). A: (M,K). B rows at stride ldB. BM,BN in {64,128}.
// EP: 1 +bias->f32, 2 +bias,relu->bf16, 3 elu->f32, 5 plain->bf16, 6 qkv(+bias,Q-scaled)->bf16
template<int EP, int BM, int BN>
__global__ __launch_bounds__(256) void gemm_bf(const ushort* __restrict__ A,
                                               const ushort* __restrict__ B,
                                               const float* __restrict__ bias,
                                               float* __restrict__ Cf,
                                               ushort* __restrict__ Cb,
                                               int M, int N, int K, int ldB,
                                               long long sA, long long sB, long long sC)
{
    __shared__ ushort As[2][BM][32];   // linear: gload_lds dest must be contiguous
    __shared__ ushort Bs[2][BN][32];
    A += (size_t)blockIdx.z * sA;
    B += (size_t)blockIdx.z * sB;

    const int t  = threadIdx.x;
    const int m0 = blockIdx.y * BM, n0 = blockIdx.x * BN;
    const int lane = t & 63, lo = lane & 15, hi = lane >> 4;
    const int w = t >> 6;
    constexpr int NI = BM / 32, NJ = BN / 32;
    const int wr = (w >> 1) * (BM / 2);
    const int wc = (w & 1) * (BN / 2);

    const int lr16 = lane >> 2;        // row within a 16-row staging group
    const int lc8  = (lane & 3) * 8;   // k-chunk (ushorts)

    f32x4 acc[NI][NJ];
    const f32x4 zero = {0.f, 0.f, 0.f, 0.f};
    #pragma unroll
    for (int i = 0; i < NI; i++)
        #pragma unroll
        for (int j = 0; j < NJ; j++) acc[i][j] = zero;

    // stage tile k0 -> buffer buf (async; drained by next __syncthreads)
    auto stage = [&](int buf, int k0) {
        if constexpr (BM == 128) {
            gl16(A + (size_t)(m0 + 32*w      + lr16) * K + k0 + lc8, &As[buf][32*w][0]);
            gl16(A + (size_t)(m0 + 32*w + 16 + lr16) * K + k0 + lc8, &As[buf][32*w + 16][0]);
        } else {
            gl16(A + (size_t)(m0 + 16*w + lr16) * K + k0 + lc8, &As[buf][16*w][0]);
        }
        if constexpr (BN == 128) {
            gl16(B + (size_t)(n0 + 32*w      + lr16) * ldB + k0 + lc8, &Bs[buf][32*w][0]);
            gl16(B + (size_t)(n0 + 32*w + 16 + lr16) * ldB + k0 + lc8, &Bs[buf][32*w + 16][0]);
        } else {
            gl16(B + (size_t)(n0 + 16*w + lr16) * ldB + k0 + lc8, &Bs[buf][16*w][0]);
        }
    };

    stage(0, 0);                        // prologue
    const int NT = K >> 5;
    for (int it = 0; it < NT; it++) {
        const int cur = it & 1;
        __syncthreads();                // drains vmcnt: buf[cur] ready; prev reads of buf[cur^1] done
        if (it + 1 < NT) stage(cur ^ 1, (it + 1) << 5);   // async prefetch overlaps MFMA phase

        short8 afr[NI], bfr[NJ];
        #pragma unroll
        for (int i = 0; i < NI; i++) afr[i] = *(const short8*)&As[cur][wr + i*16 + lo][hi * 8];
        #pragma unroll
        for (int j = 0; j < NJ; j++) bfr[j] = *(const short8*)&Bs[cur][wc + j*16 + lo][hi * 8];
        #pragma unroll
        for (int i = 0; i < NI; i++)
            #pragma unroll
            for (int j = 0; j < NJ; j++)
                acc[i][j] = __builtin_amdgcn_mfma_f32_16x16x32_bf16(afr[i], bfr[j], acc[i][j], 0, 0, 0);
    }

    if (EP == 2 || EP == 5 || EP == 6) Cb += (size_t)blockIdx.z * sC;
    else                               Cf += (size_t)blockIdx.z * sC;
    #pragma unroll
    for (int j = 0; j < NJ; j++) {
        const int col = n0 + wc + j * 16 + lo;
        float bj = (EP == 1 || EP == 2 || EP == 6) ? bias[col] : 0.f;
        #pragma unroll
        for (int i = 0; i < NI; i++) {
            const int rbase = m0 + wr + i * 16 + hi * 4;
            #pragma unroll
            for (int r = 0; r < 4; r++) {
                float v = acc[i][j][r] + bj;
                if (EP == 3) v = v > 0.f ? v : expm1f(v);
                if (EP == 2) v = fmaxf(v, 0.f);
                if (EP == 6 && col < DM) v *= QSCALE;
                if (EP == 2 || EP == 5 || EP == 6) Cb[(size_t)(rbase + r) * N + col] = f2bf(v);
                else                               Cf[(size_t)(rbase + r) * N + col] = v;
            }
        }
    }
}

// ---------------- LayerNorm(a + r) * g + b, 4 rows / block ----------------
template<bool WB>
__global__ __launch_bounds__(256) void ln_k(const float* __restrict__ a,
                                            const float* __restrict__ r,
                                            const float* __restrict__ g,
                                            const float* __restrict__ be,
                                            float* __restrict__ o,
                                            ushort* __restrict__ ob)
{
    const size_t row = (size_t)blockIdx.x * 4 + (threadIdx.x >> 6);
    const int l = threadIdx.x & 63;
    const float* pa = a + row * DM;
    const float* pr = r + row * DM;
    float v[4]; float s = 0.f;
    #pragma unroll
    for (int i = 0; i < 4; i++) { v[i] = pa[l + 64*i] + pr[l + 64*i]; s += v[i]; }
    #pragma unroll
    for (int off = 32; off; off >>= 1) s += __shfl_xor(s, off, 64);
    float mu = s * (1.0f / DM);
    float q = 0.f;
    #pragma unroll
    for (int i = 0; i < 4; i++) { float d = v[i] - mu; q += d * d; }
    #pragma unroll
    for (int off = 32; off; off >>= 1) q += __shfl_xor(q, off, 64);
    float rs = rsqrtf(q * (1.0f / DM) + EPSV);
    #pragma unroll
    for (int i = 0; i < 4; i++) {
        int c = l + 64*i;
        float out = (v[i] - mu) * rs * g[c] + be[c];
        o[row * DM + c] = out;
        if (WB) ob[row * DM + c] = f2bf(out);
    }
}

// ---------------- GAT masked softmax (exp2 domain) -> normalized P (bf16) ----------------
__global__ __launch_bounds__(256) void gat_sm_k(const int* __restrict__ adj,
                                                const float* __restrict__ f1,
                                                const float* __restrict__ f2,
                                                ushort* __restrict__ P)
{
    __shared__ float red[8];
    const int i = blockIdx.x, b = i >> 10;
    const int t = threadIdx.x;
    const int4 a4 = *(const int4*)&adj[(size_t)i * SEQ + 4 * t];
    const float4 f4 = *(const float4*)&f2[(size_t)(b << 10) + 4 * t];
    const float f1i = f1[i];
    float e[4];
    e[0] = a4.x > 0 ? f1i + f4.x : NEGV;
    e[1] = a4.y > 0 ? f1i + f4.y : NEGV;
    e[2] = a4.z > 0 ? f1i + f4.z : NEGV;
    e[3] = a4.w > 0 ? f1i + f4.w : NEGV;
    float mx = fmaxf(fmaxf(e[0], e[1]), fmaxf(e[2], e[3]));
    #pragma unroll
    for (int off = 32; off; off >>= 1) mx = fmaxf(mx, __shfl_xor(mx, off, 64));
    if ((t & 63) == 0) red[t >> 6] = mx;
    __syncthreads();
    mx = fmaxf(fmaxf(red[0], red[1]), fmaxf(red[2], red[3]));
    float s = 0.f;
    #pragma unroll
    for (int u = 0; u < 4; u++) { e[u] = exp2f(e[u] - mx); s += e[u]; }
    #pragma unroll
    for (int off = 32; off; off >>= 1) s += __shfl_xor(s, off, 64);
    if ((t & 63) == 0) red[4 + (t >> 6)] = s;
    __syncthreads();
    float inv = 1.0f / (red[4] + red[5] + red[6] + red[7]);
    ushort4 o;
    o.x = f2bf(e[0] * inv); o.y = f2bf(e[1] * inv);
    o.z = f2bf(e[2] * inv); o.w = f2bf(e[3] * inv);
    *(ushort4*)&P[(size_t)i * SEQ + 4 * t] = o;
}

// ---------------- MHA v4 (unchanged) ----------------
__device__ __forceinline__ int vt_idx(int d, int kv) { return d * 72 + ((d >> 3) & 3) * 16 + kv; }
constexpr int VTSZ = 32 * 72 + 3 * 16 + 8;

__global__ __launch_bounds__(256) void mha_k(const ushort* __restrict__ qkv,
                                             ushort* __restrict__ ctxb)
{
    __shared__ ushort Ks[2][64][40];
    __shared__ ushort Vt[2][VTSZ];
    __shared__ ushort Ps[64][72];

    const int blk = blockIdx.x;
    const int qt = blk & 15, h = (blk >> 4) & 7, b = blk >> 7;
    const int i0 = qt << 6;
    const int t = threadIdx.x;
    const int w = t >> 6, lane = t & 63, lo = lane & 15, hi = lane >> 4;
    const int gsh = lane & 48;
    const size_t base = (size_t)b * SEQ * 768;

    const short8 aQ = *(const short8*)(qkv + base + (size_t)(i0 + 16*w + lo) * 768 + h * HDIM + hi * 8);
    short8 ones;
    #pragma unroll
    for (int e = 0; e < 8; e++) ones[e] = (short)0x3F80;

    const int srow = t >> 2, scb = (t & 3) << 3;
    const int vcol = (srow & 32) | ((srow & 15) << 1) | ((srow >> 4) & 1);
    {
        const ushort* p0 = qkv + base + (size_t)srow * 768 + h * HDIM;
        short8 k0 = *(const short8*)(p0 + 256 + scb);
        short8 v0 = *(const short8*)(p0 + 512 + scb);
        *(short8*)&Ks[0][srow][scb] = k0;
        #pragma unroll
        for (int e = 0; e < 8; e++) Vt[0][vt_idx(scb + e, vcol)] = (ushort)v0[e];
    }

    float m_run[4], l_run[4];
    f32x4 O0 = {0.f, 0.f, 0.f, 0.f}, O1 = {0.f, 0.f, 0.f, 0.f};
    #pragma unroll
    for (int r = 0; r < 4; r++) { m_run[r] = -3.0e38f; l_run[r] = 0.f; }
    const f32x4 zero = {0.f, 0.f, 0.f, 0.f};

    short8 kreg, vreg;
    for (int it = 0; it < 16; it++) {
        const int cur = it & 1;
        if (it < 15) {
            const ushort* nb = qkv + base + (size_t)((it + 1) * 64 + srow) * 768 + h * HDIM;
            kreg = *(const short8*)(nb + 256 + scb);
            vreg = *(const short8*)(nb + 512 + scb);
        }
        __syncthreads();

        f32x4 S[4];
        #pragma unroll
        for (int jt = 0; jt < 4; jt++) {
            short8 bK = *(const short8*)&Ks[cur][16 * jt + lo][hi * 8];
            S[jt] = __builtin_amdgcn_mfma_f32_16x16x32_bf16(aQ, bK, zero, 0, 0, 0);
        }

        float mxl[4];
        bool any = false;
        #pragma unroll
        for (int r = 0; r < 4; r++) {
            mxl[r] = fmaxf(fmaxf(S[0][r], S[1][r]), fmaxf(S[2][r], S[3][r]));
            any = any || (mxl[r] > m_run[r] + 8.f);
        }
        unsigned long long bal = __ballot(any);
        if ((bal >> gsh) & 0xffffULL) {
            #pragma unroll
            for (int r = 0; r < 4; r++) {
                float mx = mxl[r];
                #pragma unroll
                for (int off = 8; off; off >>= 1) mx = fmaxf(mx, __shfl_xor(mx, off, 16));
                float mnew = fmaxf(m_run[r], mx);
                float sc = exp2f(m_run[r] - mnew);
                m_run[r] = mnew;
                l_run[r] *= sc; O0[r] *= sc; O1[r] *= sc;
            }
        }
        #pragma unroll
        for (int r = 0; r < 4; r++) {
            const int row = 16 * w + 4 * hi + r;
            unsigned u01 = cvt_pk_bf16(exp2f(S[0][r] - m_run[r]), exp2f(S[1][r] - m_run[r]));
            unsigned u23 = cvt_pk_bf16(exp2f(S[2][r] - m_run[r]), exp2f(S[3][r] - m_run[r]));
            *(unsigned*)&Ps[row][2 * lo]      = u01;
            *(unsigned*)&Ps[row][32 + 2 * lo] = u23;
        }

        f32x4 O2 = zero;
        #pragma unroll
        for (int kt = 0; kt < 2; kt++) {
            short8 aP  = *(const short8*)&Ps[16 * w + lo][32 * kt + hi * 8];
            short8 bV0 = *(const short8*)&Vt[cur][vt_idx(lo,      32 * kt + hi * 8)];
            short8 bV1 = *(const short8*)&Vt[cur][vt_idx(16 + lo, 32 * kt + hi * 8)];
            O0 = __builtin_amdgcn_mfma_f32_16x16x32_bf16(aP, bV0, O0, 0, 0, 0);
            O1 = __builtin_amdgcn_mfma_f32_16x16x32_bf16(aP, bV1, O1, 0, 0, 0);
            O2 = __builtin_amdgcn_mfma_f32_16x16x32_bf16(aP, ones, O2, 0, 0, 0);
        }
        #pragma unroll
        for (int r = 0; r < 4; r++) l_run[r] += O2[r];

        if (it < 15) {
            *(short8*)&Ks[cur ^ 1][srow][scb] = kreg;
            #pragma unroll
            for (int e = 0; e < 8; e++) Vt[cur ^ 1][vt_idx(scb + e, vcol)] = (ushort)vreg[e];
        }
    }

    #pragma unroll
    for (int r = 0; r < 4; r++) {
        float inv = 1.0f / l_run[r];
        size_t row = (size_t)b * SEQ + i0 + 16 * w + 4 * hi + r;
        ctxb[row * DM + h * HDIM + lo]      = f2bf(O0[r] * inv);
        ctxb[row * DM + h * HDIM + 16 + lo] = f2bf(O1[r] * inv);
    }
}

extern "C" void kernel_launch(void* const* d_in, const int* in_sizes, int n_in,
                              void* d_out, int out_size, void* d_ws, size_t ws_size,
                              hipStream_t stream)
{
    const float* src        = (const float*)d_in[0];
    const int*   adj        = (const int*)  d_in[1];
    const float* W_gat      = (const float*)d_in[2];
    const float* a_gat      = (const float*)d_in[3];
    const float* in_proj_w  = (const float*)d_in[4];
    const float* in_proj_b  = (const float*)d_in[5];
    const float* out_proj_w = (const float*)d_in[6];
    const float* out_proj_b = (const float*)d_in[7];
    const float* lin1_w     = (const float*)d_in[8];
    const float* lin1_b     = (const float*)d_in[9];
    const float* lin2_w     = (const float*)d_in[10];
    const float* lin2_b     = (const float*)d_in[11];
    const float* ln1_g      = (const float*)d_in[12];
    const float* ln1_b_     = (const float*)d_in[13];
    const float* ln2_g      = (const float*)d_in[14];
    const float* ln2_b_     = (const float*)d_in[15];
    const float* ln3_g      = (const float*)d_in[16];
    const float* ln3_b_     = (const float*)d_in[17];

    char* base = (char*)d_ws;
    const size_t MB = 1024 * 1024;
    float*  tmp   = (float*) (base + 0 * MB);
    float*  x     = (float*) (base + 8 * MB);
    float*  y     = (float*) (base + 16 * MB);
    ushort* P_bf  = (ushort*)(base + 24 * MB);
    ushort* qkvb  = (ushort*)(base + 24 * MB);
    ushort* ff1b  = (ushort*)(base + 24 * MB);
    ushort* srcb  = (ushort*)(base + 56 * MB);
    ushort* WhTb  = (ushort*)(base + 60 * MB);
    ushort* xb    = (ushort*)(base + 64 * MB);
    ushort* yb    = (ushort*)(base + 68 * MB);
    ushort* ctxb  = (ushort*)(base + 72 * MB);
    float*  f1    = (float*) (base + 76 * MB);
    float*  f2    = f1 + ROWS;
    float*  w1    = f2 + ROWS;
    float*  w2    = w1 + DM;
    ushort* wgTb  = (ushort*)(base + 77 * MB);
    ushort* ipwb  = wgTb + 65536;
    ushort* opwb  = ipwb + 196608;
    ushort* l1wb  = opwb + 65536;
    ushort* l2wb  = l1wb + 524288;

    dim3 b256(256);

    CastArgs ca;
    ca.in[0] = src;       ca.out[0] = srcb; ca.n4[0] = 2097152 / 4;
    ca.in[1] = in_proj_w; ca.out[1] = ipwb; ca.n4[1] = 196608 / 4;
    ca.in[2] = out_proj_w;ca.out[2] = opwb; ca.n4[2] = 65536 / 4;
    ca.in[3] = lin1_w;    ca.out[3] = l1wb; ca.n4[3] = 524288 / 4;
    ca.in[4] = lin2_w;    ca.out[4] = l2wb; ca.n4[4] = 524288 / 4;
    castall_k<<<(2097152 + 196608 + 65536 + 524288 + 524288) / 4 / 256, b256, 0, stream>>>(ca);
    tcast_k<<<dim3(8, 8), b256, 0, stream>>>(W_gat, wgTb, 256, 256);

    // --- GAT ---
    w12_k<<<64, b256, 0, stream>>>(W_gat, a_gat, w1, w2);
    f12_k<<<ROWS / 4, b256, 0, stream>>>(src, w1, w2, f1, f2);
    // WhT = W_gat^T @ src^T -> bf16 [256][8192]
    gemm_bf<5, 64, 64><<<dim3(ROWS/64, DM/64, 1), b256, 0, stream>>>(wgTb, srcb, nullptr, nullptr, WhTb,
                                                                     DM, ROWS, DM, DM, 0, 0, 0);
    gat_sm_k<<<ROWS, b256, 0, stream>>>(adj, f1, f2, P_bf);
    gemm_bf<3, 64, 64><<<dim3(DM/64, SEQ/64, 8), b256, 0, stream>>>(P_bf, WhTb, nullptr, tmp, nullptr,
                                                                    SEQ, DM, SEQ, ROWS,
                                                                    (long long)SEQ * SEQ, (long long)SEQ, (long long)SEQ * DM);
    ln_k<true><<<ROWS / 4, b256, 0, stream>>>(src, tmp, ln1_g, ln1_b_, x, xb);

    // --- MHA ---
    gemm_bf<6, 128, 64><<<dim3(768/64, ROWS/128, 1), b256, 0, stream>>>(xb, ipwb, in_proj_b, nullptr, qkvb,
                                                                        ROWS, 768, DM, DM, 0, 0, 0);
    mha_k<<<BATCH * NH * (SEQ / 64), b256, 0, stream>>>(qkvb, ctxb);
    gemm_bf<1, 64, 64><<<dim3(DM/64, ROWS/64, 1), b256, 0, stream>>>(ctxb, opwb, out_proj_b, tmp, nullptr,
                                                                     ROWS, DM, DM, DM, 0, 0, 0);
    ln_k<true><<<ROWS / 4, b256, 0, stream>>>(x, tmp, ln2_g, ln2_b_, y, yb);

    // --- FFN ---
    gemm_bf<2, 128, 128><<<dim3(DF/128, ROWS/128, 1), b256, 0, stream>>>(yb, l1wb, lin1_b, nullptr, ff1b,
                                                                         ROWS, DF, DM, DM, 0, 0, 0);
    gemm_bf<1, 64, 64><<<dim3(DM/64, ROWS/64, 1), b256, 0, stream>>>(ff1b, l2wb, lin2_b, tmp, nullptr,
                                                                     ROWS, DM, DF, DF, 0, 0, 0);
    ln_k<false><<<ROWS / 4, b256, 0, stream>>>(y, tmp, ln3_g, ln3_b_, (float*)d_out, nullptr);
}